// Round 5
// baseline (85.616 us; speedup 1.0000x reference)
//
#include <hip/hip_runtime.h>
#include <math.h>

#define N_B 64
#define T_LEN 2048
#define D_DIM 512
#define C_CH 32                 // chunks per batch
#define TC (T_LEN / C_CH)       // 64 rows per chunk
#define RW (TC / 4)             // 16 rows per wave
#define NEG (-1e9f)

// ws layout: ctl[0]=atomic cursor, ctl[1]=total, ctl[2..]=items (c-major).
// floats at +16KB: m_ws[N*C], l_ws[N*C], o_ws[N*C*D].

__device__ __forceinline__ float dot8(const float4& qa, const float4& qb,
                                      const float4& ka, const float4& kb) {
    return qa.x * ka.x + qa.y * ka.y + qa.z * ka.z + qa.w * ka.w
         + qb.x * kb.x + qb.y * kb.y + qb.z * kb.z + qb.w * kb.w;
}

// ---------------------------------------------------------------------------
// Setup: compact active (n,c) chunks into a c-major work list; init stats.
// Chunk (n,c) is active iff len_n==0 (V-mean work) or c*TC < len_n.
// ---------------------------------------------------------------------------
__global__ __launch_bounds__(64) void attn_setup(
    const int* __restrict__ lens,
    int* __restrict__ ctl,
    float* __restrict__ m_ws,
    float* __restrict__ l_ws)
{
    const int tid = threadIdx.x;   // one wave
    for (int i = tid; i < N_B * C_CH; i += 64) {
        m_ws[i] = -INFINITY;
        l_ws[i] = 0.0f;
    }
    if (tid == 0) ctl[0] = 0;

    int cnt = 0;
    if (tid < C_CH) {
        for (int n = 0; n < N_B; ++n) {
            const int len = lens[n];
            if (len == 0 || tid * TC < len) ++cnt;
        }
    }
    // inclusive scan across the wave
    int incl = cnt;
    #pragma unroll
    for (int off = 1; off < 64; off <<= 1) {
        const int y = __shfl_up(incl, off);
        if (tid >= off) incl += y;
    }
    const int base = incl - cnt;
    if (tid == C_CH - 1) ctl[1] = incl;   // total items
    if (tid < C_CH) {
        int idx = base;
        for (int n = 0; n < N_B; ++n) {
            const int len = lens[n];
            if (len == 0 || tid * TC < len)
                ctl[2 + idx++] = (n << 8) | tid;
        }
    }
}

// ---------------------------------------------------------------------------
// Partial: blocks dynamically pop active chunks. Per chunk: 4 waves, each owns
// RW contiguous rows, online softmax in registers (R4 inner loop), merge via
// LDS, write (m, l, o) partials.
// ---------------------------------------------------------------------------
__global__ __launch_bounds__(256) void attn_partial(
    const float* __restrict__ q,     // (N, D)
    const float* __restrict__ key,   // (T, N, D)
    const float* __restrict__ val,   // (T, N, D)
    const int*   __restrict__ lens,  // (N)
    int*   __restrict__ ctl,
    float* __restrict__ m_ws,        // (N, C)
    float* __restrict__ l_ws,        // (N, C)
    float* __restrict__ o_ws)        // (N, C, D)
{
    const int tid  = threadIdx.x;
    const int wave = tid >> 6;
    const int lane = tid & 63;
    const int d0   = 2 * tid;
    const size_t rstride = (size_t)N_B * D_DIM;

    const int total = ctl[1];

    __shared__ float acc_sm[4][D_DIM];
    __shared__ float ml_sm[4][2];
    __shared__ int   w_sm;

    for (;;) {
        __syncthreads();   // protect acc_sm/w_sm reuse across items
        if (tid == 0) w_sm = atomicAdd(&ctl[0], 1);
        __syncthreads();
        const int w = w_sm;
        if (w >= total) break;

        const int item  = ctl[2 + w];
        const int n     = item >> 8;
        const int c     = item & 255;
        const int len_n = lens[n];
        const int wstart = c * TC + wave * RW;

        float acc[8];
        #pragma unroll
        for (int j = 0; j < 8; ++j) acc[j] = 0.0f;
        float m = -INFINITY, l = 0.0f;

        if (len_n == 0) {
            // Reference: all energies NEG -> uniform softmax -> mean of value.
            const float* vr = val + ((size_t)wstart * N_B + n) * D_DIM + 8 * lane;
            for (int i = 0; i < RW; ++i) {
                const float4 va = *reinterpret_cast<const float4*>(vr);
                const float4 vb = *reinterpret_cast<const float4*>(vr + 4);
                vr += rstride;
                acc[0] += va.x; acc[1] += va.y; acc[2] += va.z; acc[3] += va.w;
                acc[4] += vb.x; acc[5] += vb.y; acc[6] += vb.z; acc[7] += vb.w;
            }
            m = NEG;
            l = (float)RW;
        } else {
            int nact = len_n - wstart;
            if (nact > RW) nact = RW;
            if (nact > 0) {
                const float4* q4 = reinterpret_cast<const float4*>(
                    q + (size_t)n * D_DIM) + 2 * lane;
                const float4 qa = q4[0];
                const float4 qb = q4[1];

                const float* kr = key + ((size_t)wstart * N_B + n) * D_DIM + 8 * lane;
                const float* vr = val + ((size_t)wstart * N_B + n) * D_DIM + 8 * lane;

                float4 ka = *reinterpret_cast<const float4*>(kr);
                float4 kb = *reinterpret_cast<const float4*>(kr + 4);
                float4 na = ka, nb = kb;

                for (int i = 0; i < nact; ++i) {
                    const float4 va = *reinterpret_cast<const float4*>(vr);
                    const float4 vb = *reinterpret_cast<const float4*>(vr + 4);
                    vr += rstride;
                    if (i + 1 < nact) {
                        na = *reinterpret_cast<const float4*>(kr + rstride);
                        nb = *reinterpret_cast<const float4*>(kr + rstride + 4);
                    }
                    kr += rstride;

                    float e = dot8(qa, qb, ka, kb);
                    #pragma unroll
                    for (int off = 32; off; off >>= 1) e += __shfl_xor(e, off);

                    if (e > m) {                        // wave-uniform
                        const float sc = __expf(m - e); // first iter: 0
                        l *= sc;
                        #pragma unroll
                        for (int j = 0; j < 8; ++j) acc[j] *= sc;
                        m = e;
                    }
                    const float p = __expf(e - m);
                    l += p;
                    acc[0] += p * va.x; acc[1] += p * va.y;
                    acc[2] += p * va.z; acc[3] += p * va.w;
                    acc[4] += p * vb.x; acc[5] += p * vb.y;
                    acc[6] += p * vb.z; acc[7] += p * vb.w;

                    ka = na; kb = nb;
                }
            }
            // nact <= 0: stays (-inf, 0, 0) -> zero weight at merge.
        }

        // ---- merge 4 waves ----
        *reinterpret_cast<float4*>(&acc_sm[wave][8 * lane]) =
            make_float4(acc[0], acc[1], acc[2], acc[3]);
        *reinterpret_cast<float4*>(&acc_sm[wave][8 * lane + 4]) =
            make_float4(acc[4], acc[5], acc[6], acc[7]);
        if (lane == 0) { ml_sm[wave][0] = m; ml_sm[wave][1] = l; }
        __syncthreads();

        const float m0 = ml_sm[0][0], m1 = ml_sm[1][0];
        const float m2 = ml_sm[2][0], m3 = ml_sm[3][0];
        const float M  = fmaxf(fmaxf(m0, m1), fmaxf(m2, m3));
        const float s0 = __expf(m0 - M), s1 = __expf(m1 - M);
        const float s2 = __expf(m2 - M), s3 = __expf(m3 - M);

        float2 r;
        r.x = s0 * acc_sm[0][d0]     + s1 * acc_sm[1][d0]
            + s2 * acc_sm[2][d0]     + s3 * acc_sm[3][d0];
        r.y = s0 * acc_sm[0][d0 + 1] + s1 * acc_sm[1][d0 + 1]
            + s2 * acc_sm[2][d0 + 1] + s3 * acc_sm[3][d0 + 1];
        *reinterpret_cast<float2*>(
            o_ws + ((size_t)n * C_CH + c) * D_DIM + d0) = r;

        if (tid == 0) {
            m_ws[n * C_CH + c] = M;
            l_ws[n * C_CH + c] = s0 * ml_sm[0][1] + s1 * ml_sm[1][1]
                               + s2 * ml_sm[2][1] + s3 * ml_sm[3][1];
        }
    }
}

// ---------------------------------------------------------------------------
// Combine: per batch, log-sum-exp merge of C chunk partials.
// Grid (N, 2): block (n, h) handles d = h*256 + tid (scalar, coalesced).
// ---------------------------------------------------------------------------
__global__ __launch_bounds__(256) void attn_combine(
    const float* __restrict__ m_ws,
    const float* __restrict__ l_ws,
    const float* __restrict__ o_ws,
    float* __restrict__ out)
{
    const int n   = blockIdx.x;
    const int d   = blockIdx.y * 256 + threadIdx.x;
    const int tid = threadIdx.x;

    __shared__ float s_sm[64];
    __shared__ float S_sm;

    if (tid < 64) {
        const float m = (tid < C_CH) ? m_ws[n * C_CH + tid] : -INFINITY;
        float M = m;
        #pragma unroll
        for (int off = 32; off; off >>= 1) M = fmaxf(M, __shfl_xor(M, off));
        const float s = (tid < C_CH) ? __expf(m - M) : 0.0f;  // -inf -> 0
        s_sm[tid] = s;
        float S = s * ((tid < C_CH) ? l_ws[n * C_CH + tid] : 0.0f);
        #pragma unroll
        for (int off = 32; off; off >>= 1) S += __shfl_xor(S, off);
        if (tid == 0) S_sm = S;
    }
    __syncthreads();

    const float inv = 1.0f / S_sm;
    float acc = 0.0f;
    const float* op = o_ws + (size_t)n * C_CH * D_DIM + d;
    for (int c = 0; c < C_CH; ++c) {
        const float s = s_sm[c];
        if (s != 0.0f) acc += s * op[(size_t)c * D_DIM];
    }
    out[(size_t)n * D_DIM + d] = acc * inv;
}

extern "C" void kernel_launch(void* const* d_in, const int* in_sizes, int n_in,
                              void* d_out, int out_size, void* d_ws, size_t ws_size,
                              hipStream_t stream) {
    const float* q    = (const float*)d_in[0];
    const float* key  = (const float*)d_in[1];
    const float* val  = (const float*)d_in[2];
    const int*   lens = (const int*)d_in[3];
    float*       out  = (float*)d_out;

    int*   ctl  = (int*)d_ws;
    float* m_ws = (float*)((char*)d_ws + 16384);
    float* l_ws = m_ws + N_B * C_CH;
    float* o_ws = l_ws + N_B * C_CH;   // 4 MB; ws is ~1 GB

    attn_setup<<<1, 64, 0, stream>>>(lens, ctl, m_ws, l_ws);
    attn_partial<<<1024, 256, 0, stream>>>(q, key, val, lens, ctl,
                                           m_ws, l_ws, o_ws);
    attn_combine<<<dim3(N_B, D_DIM / 256), 256, 0, stream>>>(m_ws, l_ws,
                                                             o_ws, out);
}

// Round 6
// 60.067 us; speedup vs baseline: 1.4253x; 1.4253x over previous
//
#include <hip/hip_runtime.h>
#include <math.h>

#define N_B 64
#define T_LEN 2048
#define D_DIM 512
#define NEG (-1e9f)
#define G_BLK 2048              // partial-kernel grid (8 blocks/CU, all resident)
#define MIN_W 16                // floor on rows/block (bounds J_MAX)
#define J_MAX 132               // >= T_LEN/MIN_W + 2 partial slots per batch

// ws: ctl[0]=total rows, ctl[1..65]=exclusive prefix s_0..s_64 (s_0=0).
// floats at +4KB: m_ws[N*J_MAX], l_ws[N*J_MAX], o_ws[N*J_MAX*D].

__device__ __forceinline__ float dot8(const float4& qa, const float4& qb,
                                      const float4& ka, const float4& kb) {
    return qa.x * ka.x + qa.y * ka.y + qa.z * ka.z + qa.w * ka.w
         + qb.x * kb.x + qb.y * kb.y + qb.z * kb.z + qb.w * kb.w;
}

// ---------------------------------------------------------------------------
// Setup: prefix-sum of useful rows per batch (len==0 -> all T rows of V-mean).
// ---------------------------------------------------------------------------
__global__ __launch_bounds__(64) void attn_setup(
    const int* __restrict__ lens, int* __restrict__ ctl)
{
    const int tid = threadIdx.x;          // one wave of 64
    const int len = lens[tid];
    int incl = (len == 0) ? T_LEN : len;  // useful rows for batch tid
    #pragma unroll
    for (int off = 1; off < 64; off <<= 1) {
        const int y = __shfl_up(incl, off);
        if (tid >= off) incl += y;
    }
    if (tid == 0) ctl[1] = 0;
    ctl[2 + tid] = incl;                  // s_{tid+1}
    if (tid == 63) ctl[0] = incl;         // total
}

// ---------------------------------------------------------------------------
// Partial: block b owns global rows [b*W, (b+1)*W) of the flattened list —
// exact per-block balance. Per batch-segment: 4 waves (strided by 4 rows) run
// the R4 online-softmax loop in registers, merge via LDS, write partial slot
// j = b - floor(s_n / W).
// ---------------------------------------------------------------------------
__global__ __launch_bounds__(256) void attn_partial(
    const float* __restrict__ q,     // (N, D)
    const float* __restrict__ key,   // (T, N, D)
    const float* __restrict__ val,   // (T, N, D)
    const int*   __restrict__ lens,  // (N)
    const int*   __restrict__ ctl,
    float* __restrict__ m_ws,        // (N, J_MAX)
    float* __restrict__ l_ws,        // (N, J_MAX)
    float* __restrict__ o_ws)        // (N, J_MAX, D)
{
    const int tid  = threadIdx.x;
    const int wave = tid >> 6;
    const int lane = tid & 63;
    const int d0   = 2 * tid;
    const size_t rstride = (size_t)N_B * D_DIM;   // t-stride in floats

    __shared__ int   pre_sm[N_B + 1];
    __shared__ float acc_sm[4][D_DIM];
    __shared__ float ml_sm[4][2];

    if (tid <= N_B) pre_sm[tid] = ctl[1 + tid];
    __syncthreads();

    const int total = pre_sm[N_B];
    int W = (total + G_BLK - 1) / G_BLK;
    if (W < MIN_W) W = MIN_W;
    const int r0 = blockIdx.x * W;
    if (r0 >= total) return;
    const int r1 = min(r0 + W, total);

    // binary search: largest n with s_n <= r0
    int lo = 0, hi = N_B;
    while (hi - lo > 1) {
        const int mid = (lo + hi) >> 1;
        if (pre_sm[mid] <= r0) lo = mid; else hi = mid;
    }
    int n = lo;
    int r = r0;

    while (r < r1) {
        const int sn    = pre_sm[n];
        const int sn1   = pre_sm[n + 1];
        const int ta    = r - sn;                  // local row range [ta, tb)
        const int tb    = min(r1, sn1) - sn;
        const int j     = blockIdx.x - (sn / W);   // deterministic slot
        const int len_n = lens[n];

        float acc[8];
        #pragma unroll
        for (int jj = 0; jj < 8; ++jj) acc[jj] = 0.0f;
        float m = -INFINITY, l = 0.0f;

        if (len_n == 0) {
            // all energies NEG -> uniform weights: sum V, l = row count.
            int cnt = 0;
            const float* vr = val + ((size_t)(ta + wave) * N_B + n) * D_DIM
                            + 8 * lane;
            for (int t = ta + wave; t < tb; t += 4) {
                const float4 va = *reinterpret_cast<const float4*>(vr);
                const float4 vb = *reinterpret_cast<const float4*>(vr + 4);
                vr += 4 * rstride;
                acc[0] += va.x; acc[1] += va.y; acc[2] += va.z; acc[3] += va.w;
                acc[4] += vb.x; acc[5] += vb.y; acc[6] += vb.z; acc[7] += vb.w;
                ++cnt;
            }
            m = NEG;
            l = (float)cnt;
        } else {
            // every row in [ta, tb) is unmasked by construction.
            int t = ta + wave;
            if (t < tb) {
                const float4* q4 = reinterpret_cast<const float4*>(
                    q + (size_t)n * D_DIM) + 2 * lane;
                const float4 qa = q4[0];
                const float4 qb = q4[1];

                const float* kr = key + ((size_t)t * N_B + n) * D_DIM + 8 * lane;
                const float* vr = val + ((size_t)t * N_B + n) * D_DIM + 8 * lane;

                float4 ka = *reinterpret_cast<const float4*>(kr);
                float4 kb = *reinterpret_cast<const float4*>(kr + 4);
                float4 na = ka, nb = kb;

                for (; t < tb; t += 4) {
                    const float4 va = *reinterpret_cast<const float4*>(vr);
                    const float4 vb = *reinterpret_cast<const float4*>(vr + 4);
                    vr += 4 * rstride;
                    if (t + 4 < tb) {
                        na = *reinterpret_cast<const float4*>(kr + 4 * rstride);
                        nb = *reinterpret_cast<const float4*>(kr + 4 * rstride + 4);
                    }
                    kr += 4 * rstride;

                    float e = dot8(qa, qb, ka, kb);
                    #pragma unroll
                    for (int off = 32; off; off >>= 1) e += __shfl_xor(e, off);

                    if (e > m) {                        // wave-uniform
                        const float sc = __expf(m - e); // first iter: 0
                        l *= sc;
                        #pragma unroll
                        for (int jj = 0; jj < 8; ++jj) acc[jj] *= sc;
                        m = e;
                    }
                    const float p = __expf(e - m);
                    l += p;
                    acc[0] += p * va.x; acc[1] += p * va.y;
                    acc[2] += p * va.z; acc[3] += p * va.w;
                    acc[4] += p * vb.x; acc[5] += p * vb.y;
                    acc[6] += p * vb.z; acc[7] += p * vb.w;

                    ka = na; kb = nb;
                }
            }
            // wave with no rows keeps (-inf, 0, 0) -> zero weight at merge.
        }

        // ---- merge 4 waves, write partial slot (n, j) ----
        *reinterpret_cast<float4*>(&acc_sm[wave][8 * lane]) =
            make_float4(acc[0], acc[1], acc[2], acc[3]);
        *reinterpret_cast<float4*>(&acc_sm[wave][8 * lane + 4]) =
            make_float4(acc[4], acc[5], acc[6], acc[7]);
        if (lane == 0) { ml_sm[wave][0] = m; ml_sm[wave][1] = l; }
        __syncthreads();

        const float m0 = ml_sm[0][0], m1 = ml_sm[1][0];
        const float m2 = ml_sm[2][0], m3 = ml_sm[3][0];
        const float M  = fmaxf(fmaxf(m0, m1), fmaxf(m2, m3));  // finite
        const float s0 = __expf(m0 - M), s1 = __expf(m1 - M);
        const float s2 = __expf(m2 - M), s3 = __expf(m3 - M);

        float2 rr;
        rr.x = s0 * acc_sm[0][d0]     + s1 * acc_sm[1][d0]
             + s2 * acc_sm[2][d0]     + s3 * acc_sm[3][d0];
        rr.y = s0 * acc_sm[0][d0 + 1] + s1 * acc_sm[1][d0 + 1]
             + s2 * acc_sm[2][d0 + 1] + s3 * acc_sm[3][d0 + 1];
        *reinterpret_cast<float2*>(
            o_ws + ((size_t)n * J_MAX + j) * D_DIM + d0) = rr;

        if (tid == 0) {
            m_ws[n * J_MAX + j] = M;
            l_ws[n * J_MAX + j] = s0 * ml_sm[0][1] + s1 * ml_sm[1][1]
                                + s2 * ml_sm[2][1] + s3 * ml_sm[3][1];
        }
        __syncthreads();   // protect acc_sm before next segment

        r = min(r1, sn1);
        ++n;
    }
}

// ---------------------------------------------------------------------------
// Combine: per batch n, LSE-merge its J_n = b1-b0+1 partial slots.
// Grid (N, 2): block (n, h) handles d = h*256 + tid.
// ---------------------------------------------------------------------------
__global__ __launch_bounds__(256) void attn_combine(
    const int*   __restrict__ ctl,
    const float* __restrict__ m_ws,
    const float* __restrict__ l_ws,
    const float* __restrict__ o_ws,
    float* __restrict__ out)
{
    const int n   = blockIdx.x;
    const int tid = threadIdx.x;

    __shared__ float s_sm[J_MAX];
    __shared__ float S_sm;
    __shared__ int   J_sm;

    if (tid < 64) {
        const int total = ctl[0];
        int W = (total + G_BLK - 1) / G_BLK;
        if (W < MIN_W) W = MIN_W;
        const int sn  = ctl[1 + n];
        const int sn1 = ctl[2 + n];
        const int b0  = sn / W;
        const int b1  = (sn1 - 1) / W;      // sn1 > sn always (rows >= 1)
        const int J   = b1 - b0 + 1;        // <= J_MAX
        if (tid == 0) J_sm = J;

        float mj[3], lj[3];
        float M = -INFINITY;
        #pragma unroll
        for (int k = 0; k < 3; ++k) {
            const int jdx = tid + 64 * k;
            const bool ok = (jdx < J);
            mj[k] = ok ? m_ws[n * J_MAX + jdx] : -INFINITY;
            lj[k] = ok ? l_ws[n * J_MAX + jdx] : 0.0f;
            M = fmaxf(M, mj[k]);
        }
        #pragma unroll
        for (int off = 32; off; off >>= 1) M = fmaxf(M, __shfl_xor(M, off));
        float S = 0.0f;
        #pragma unroll
        for (int k = 0; k < 3; ++k) {
            const int jdx = tid + 64 * k;
            const float s = __expf(mj[k] - M);   // -inf -> 0
            if (jdx < J) s_sm[jdx] = s;
            S += s * lj[k];
        }
        #pragma unroll
        for (int off = 32; off; off >>= 1) S += __shfl_xor(S, off);
        if (tid == 0) S_sm = S;
    }
    __syncthreads();

    const int J = J_sm;
    const float inv = 1.0f / S_sm;
    const int d = blockIdx.y * 256 + tid;
    float acc = 0.0f;
    const float* op = o_ws + (size_t)n * J_MAX * D_DIM + d;
    for (int jj = 0; jj < J; ++jj)
        acc += s_sm[jj] * op[(size_t)jj * D_DIM];
    out[(size_t)n * D_DIM + d] = acc * inv;
}

extern "C" void kernel_launch(void* const* d_in, const int* in_sizes, int n_in,
                              void* d_out, int out_size, void* d_ws, size_t ws_size,
                              hipStream_t stream) {
    const float* q    = (const float*)d_in[0];
    const float* key  = (const float*)d_in[1];
    const float* val  = (const float*)d_in[2];
    const int*   lens = (const int*)d_in[3];
    float*       out  = (float*)d_out;

    int*   ctl  = (int*)d_ws;
    float* m_ws = (float*)((char*)d_ws + 4096);
    float* l_ws = m_ws + N_B * J_MAX;
    float* o_ws = l_ws + N_B * J_MAX;     // 64*132*512*4B ~= 17.3 MB

    attn_setup<<<1, 64, 0, stream>>>(lens, ctl);
    attn_partial<<<G_BLK, 256, 0, stream>>>(q, key, val, lens, ctl,
                                            m_ws, l_ws, o_ws);
    attn_combine<<<dim3(N_B, D_DIM / 256), 256, 0, stream>>>(ctl, m_ws, l_ws,
                                                             o_ws, out);
}

// Round 7
// 54.204 us; speedup vs baseline: 1.5795x; 1.1081x over previous
//
#include <hip/hip_runtime.h>
#include <math.h>

#define N_B 64
#define T_LEN 2048
#define D_DIM 512
#define NEG (-1e9f)
#define G_BLK 2048              // partial-kernel grid (8 blocks/CU, all resident)
#define MIN_W 16                // floor on rows/block (bounds J_MAX)
#define J_MAX 132               // >= T_LEN/MIN_W + 2 partial slots per batch

// ws floats: m_ws[N*J_MAX], l_ws[N*J_MAX], o_ws[N*J_MAX*D]. No ctl/setup —
// every block recomputes the 64-entry rows-prefix from lens (L2-resident).

__device__ __forceinline__ float dot8(const float4& qa, const float4& qb,
                                      const float4& ka, const float4& kb) {
    return qa.x * ka.x + qa.y * ka.y + qa.z * ka.z + qa.w * ka.w
         + qb.x * kb.x + qb.y * kb.y + qb.z * kb.z + qb.w * kb.w;
}

// rows(n) = len_n == 0 ? T : len_n  (len==0 does uniform V-mean over all T)
__device__ __forceinline__ int useful_rows(int len) {
    return (len == 0) ? T_LEN : len;
}

// ---------------------------------------------------------------------------
// Partial: block b owns global rows [b*W, (b+1)*W) of the flattened row list —
// exact per-block balance. Per batch-segment: 4 waves (strided by 4 rows) run
// the online-softmax loop in registers, merge via LDS, write partial slot
// j = b - floor(s_n / W).
// ---------------------------------------------------------------------------
__global__ __launch_bounds__(256) void attn_partial(
    const float* __restrict__ q,     // (N, D)
    const float* __restrict__ key,   // (T, N, D)
    const float* __restrict__ val,   // (T, N, D)
    const int*   __restrict__ lens,  // (N)
    float* __restrict__ m_ws,        // (N, J_MAX)
    float* __restrict__ l_ws,        // (N, J_MAX)
    float* __restrict__ o_ws)        // (N, J_MAX, D)
{
    const int tid  = threadIdx.x;
    const int wave = tid >> 6;
    const int lane = tid & 63;
    const int d0   = 2 * tid;
    const size_t rstride = (size_t)N_B * D_DIM;   // t-stride in floats

    __shared__ int   pre_sm[N_B + 1];
    __shared__ float acc_sm[4][D_DIM];
    __shared__ float ml_sm[4][2];

    // Wave 0 computes the rows-prefix from lens (no setup kernel).
    if (wave == 0) {
        int incl = useful_rows(lens[lane]);
        #pragma unroll
        for (int off = 1; off < 64; off <<= 1) {
            const int y = __shfl_up(incl, off);
            if (lane >= off) incl += y;
        }
        if (lane == 0) pre_sm[0] = 0;
        pre_sm[1 + lane] = incl;
    }
    __syncthreads();

    const int total = pre_sm[N_B];
    int W = (total + G_BLK - 1) / G_BLK;
    if (W < MIN_W) W = MIN_W;
    const int r0 = blockIdx.x * W;
    if (r0 >= total) return;
    const int r1 = min(r0 + W, total);

    // binary search: largest n with s_n <= r0
    int lo = 0, hi = N_B;
    while (hi - lo > 1) {
        const int mid = (lo + hi) >> 1;
        if (pre_sm[mid] <= r0) lo = mid; else hi = mid;
    }
    int n = lo;
    int r = r0;

    while (r < r1) {
        const int sn    = pre_sm[n];
        const int sn1   = pre_sm[n + 1];
        const int ta    = r - sn;                  // local row range [ta, tb)
        const int tb    = min(r1, sn1) - sn;
        const int j     = blockIdx.x - (sn / W);   // deterministic slot
        const int len_n = lens[n];

        float acc[8];
        #pragma unroll
        for (int jj = 0; jj < 8; ++jj) acc[jj] = 0.0f;
        float m = -INFINITY, l = 0.0f;

        if (len_n == 0) {
            // all energies NEG -> uniform weights: sum V, l = row count.
            int cnt = 0;
            const float* vr = val + ((size_t)(ta + wave) * N_B + n) * D_DIM
                            + 8 * lane;
            for (int t = ta + wave; t < tb; t += 4) {
                const float4 va = *reinterpret_cast<const float4*>(vr);
                const float4 vb = *reinterpret_cast<const float4*>(vr + 4);
                vr += 4 * rstride;
                acc[0] += va.x; acc[1] += va.y; acc[2] += va.z; acc[3] += va.w;
                acc[4] += vb.x; acc[5] += vb.y; acc[6] += vb.z; acc[7] += vb.w;
                ++cnt;
            }
            m = NEG;
            l = (float)cnt;
        } else {
            // every row in [ta, tb) is unmasked by construction.
            int t = ta + wave;
            if (t < tb) {
                const float4* q4 = reinterpret_cast<const float4*>(
                    q + (size_t)n * D_DIM) + 2 * lane;
                const float4 qa = q4[0];
                const float4 qb = q4[1];

                const float* kr = key + ((size_t)t * N_B + n) * D_DIM + 8 * lane;
                const float* vr = val + ((size_t)t * N_B + n) * D_DIM + 8 * lane;

                float4 ka = *reinterpret_cast<const float4*>(kr);
                float4 kb = *reinterpret_cast<const float4*>(kr + 4);
                float4 na = ka, nb = kb;

                for (; t < tb; t += 4) {
                    const float4 va = *reinterpret_cast<const float4*>(vr);
                    const float4 vb = *reinterpret_cast<const float4*>(vr + 4);
                    vr += 4 * rstride;
                    if (t + 4 < tb) {
                        na = *reinterpret_cast<const float4*>(kr + 4 * rstride);
                        nb = *reinterpret_cast<const float4*>(kr + 4 * rstride + 4);
                    }
                    kr += 4 * rstride;

                    float e = dot8(qa, qb, ka, kb);
                    #pragma unroll
                    for (int off = 32; off; off >>= 1) e += __shfl_xor(e, off);

                    if (e > m) {                        // wave-uniform
                        const float sc = __expf(m - e); // first iter: 0
                        l *= sc;
                        #pragma unroll
                        for (int jj = 0; jj < 8; ++jj) acc[jj] *= sc;
                        m = e;
                    }
                    const float p = __expf(e - m);
                    l += p;
                    acc[0] += p * va.x; acc[1] += p * va.y;
                    acc[2] += p * va.z; acc[3] += p * va.w;
                    acc[4] += p * vb.x; acc[5] += p * vb.y;
                    acc[6] += p * vb.z; acc[7] += p * vb.w;

                    ka = na; kb = nb;
                }
            }
            // wave with no rows keeps (-inf, 0, 0) -> zero weight at merge.
        }

        // ---- merge 4 waves, write partial slot (n, j) ----
        *reinterpret_cast<float4*>(&acc_sm[wave][8 * lane]) =
            make_float4(acc[0], acc[1], acc[2], acc[3]);
        *reinterpret_cast<float4*>(&acc_sm[wave][8 * lane + 4]) =
            make_float4(acc[4], acc[5], acc[6], acc[7]);
        if (lane == 0) { ml_sm[wave][0] = m; ml_sm[wave][1] = l; }
        __syncthreads();

        const float m0 = ml_sm[0][0], m1 = ml_sm[1][0];
        const float m2 = ml_sm[2][0], m3 = ml_sm[3][0];
        const float M  = fmaxf(fmaxf(m0, m1), fmaxf(m2, m3));  // finite
        const float s0 = __expf(m0 - M), s1 = __expf(m1 - M);
        const float s2 = __expf(m2 - M), s3 = __expf(m3 - M);

        float2 rr;
        rr.x = s0 * acc_sm[0][d0]     + s1 * acc_sm[1][d0]
             + s2 * acc_sm[2][d0]     + s3 * acc_sm[3][d0];
        rr.y = s0 * acc_sm[0][d0 + 1] + s1 * acc_sm[1][d0 + 1]
             + s2 * acc_sm[2][d0 + 1] + s3 * acc_sm[3][d0 + 1];
        *reinterpret_cast<float2*>(
            o_ws + ((size_t)n * J_MAX + j) * D_DIM + d0) = rr;

        if (tid == 0) {
            m_ws[n * J_MAX + j] = M;
            l_ws[n * J_MAX + j] = s0 * ml_sm[0][1] + s1 * ml_sm[1][1]
                                + s2 * ml_sm[2][1] + s3 * ml_sm[3][1];
        }

        r = min(r1, sn1);
        ++n;
        if (r < r1) __syncthreads();   // acc_sm reuse only if another segment
    }
}

// ---------------------------------------------------------------------------
// Combine: per batch n, LSE-merge its J_n partial slots. Grid (N, 2):
// block (n, h) handles d = h*256 + tid. Slot loop 4-way unrolled for MLP.
// ---------------------------------------------------------------------------
__global__ __launch_bounds__(256) void attn_combine(
    const int*   __restrict__ lens,
    const float* __restrict__ m_ws,
    const float* __restrict__ l_ws,
    const float* __restrict__ o_ws,
    float* __restrict__ out)
{
    const int n   = blockIdx.x;
    const int tid = threadIdx.x;

    __shared__ float s_sm[J_MAX];
    __shared__ float S_sm;
    __shared__ int   J_sm;

    if (tid < 64) {
        // Recompute prefix from lens (one wave).
        int incl = useful_rows(lens[tid]);
        #pragma unroll
        for (int off = 1; off < 64; off <<= 1) {
            const int y = __shfl_up(incl, off);
            if (tid >= off) incl += y;
        }
        const int total = __shfl(incl, 63);
        int W = (total + G_BLK - 1) / G_BLK;
        if (W < MIN_W) W = MIN_W;
        const int sn1 = __shfl(incl, n);            // s_{n+1}
        const int sn  = (n == 0) ? 0 : __shfl(incl, n - 1);
        const int b0  = sn / W;
        const int b1  = (sn1 - 1) / W;
        const int J   = b1 - b0 + 1;                // <= J_MAX
        if (tid == 0) J_sm = J;

        float mj[3], lj[3];
        float M = -INFINITY;
        #pragma unroll
        for (int k = 0; k < 3; ++k) {
            const int jdx = tid + 64 * k;
            const bool ok = (jdx < J);
            mj[k] = ok ? m_ws[n * J_MAX + jdx] : -INFINITY;
            lj[k] = ok ? l_ws[n * J_MAX + jdx] : 0.0f;
            M = fmaxf(M, mj[k]);
        }
        #pragma unroll
        for (int off = 32; off; off >>= 1) M = fmaxf(M, __shfl_xor(M, off));
        float S = 0.0f;
        #pragma unroll
        for (int k = 0; k < 3; ++k) {
            const int jdx = tid + 64 * k;
            const float s = __expf(mj[k] - M);   // -inf -> 0
            if (jdx < J) s_sm[jdx] = s;
            S += s * lj[k];
        }
        #pragma unroll
        for (int off = 32; off; off >>= 1) S += __shfl_xor(S, off);
        if (tid == 0) S_sm = S;
    }
    __syncthreads();

    const int J = J_sm;
    const float inv = 1.0f / S_sm;
    const int d = blockIdx.y * 256 + tid;
    const float* op = o_ws + (size_t)n * J_MAX * D_DIM + d;

    // 4 independent accumulators -> 4 loads in flight.
    float a0 = 0.0f, a1 = 0.0f, a2 = 0.0f, a3 = 0.0f;
    int jj = 0;
    for (; jj + 3 < J; jj += 4) {
        a0 += s_sm[jj]     * op[(size_t)jj * D_DIM];
        a1 += s_sm[jj + 1] * op[(size_t)(jj + 1) * D_DIM];
        a2 += s_sm[jj + 2] * op[(size_t)(jj + 2) * D_DIM];
        a3 += s_sm[jj + 3] * op[(size_t)(jj + 3) * D_DIM];
    }
    for (; jj < J; ++jj)
        a0 += s_sm[jj] * op[(size_t)jj * D_DIM];

    out[(size_t)n * D_DIM + d] = (a0 + a1 + a2 + a3) * inv;
}

extern "C" void kernel_launch(void* const* d_in, const int* in_sizes, int n_in,
                              void* d_out, int out_size, void* d_ws, size_t ws_size,
                              hipStream_t stream) {
    const float* q    = (const float*)d_in[0];
    const float* key  = (const float*)d_in[1];
    const float* val  = (const float*)d_in[2];
    const int*   lens = (const int*)d_in[3];
    float*       out  = (float*)d_out;

    float* m_ws = (float*)d_ws;
    float* l_ws = m_ws + N_B * J_MAX;
    float* o_ws = l_ws + N_B * J_MAX;     // 64*132*512*4B ~= 17.3 MB

    attn_partial<<<G_BLK, 256, 0, stream>>>(q, key, val, lens,
                                            m_ws, l_ws, o_ws);
    attn_combine<<<dim3(N_B, D_DIM / 256), 256, 0, stream>>>(lens, m_ws, l_ws,
                                                             o_ws, out);
}